// Round 9
// baseline (880.273 us; speedup 1.0000x reference)
//
#include <hip/hip_runtime.h>

// BGNN-A fused kernel for MI355X (gfx950), MFMA version, atomic-free, slim-wave.
// Inputs (fp32): x[12288,64], edge_index[12288,12288] (binary 0/1), weight[64,32], bias[32]
// out (fp32): [12288, 32]
//
// Math (binary off-diagonal adjacency => E^2 == E off-diagonal):
//   xw = x @ w; B channels (128): [hi(xw)|hi(xw^2)|lo(xw)|lo(xw^2)] (bf16 hi/lo split)
//   C = E_bf16 @ B (MFMA fp32 accum); S[.,c] = C[.,c] + C[.,c+64]
//   rowsum_e[i] = sum_j E[i,j] (integer-exact VALU side-accumulate)
//   diag fixups (adj = E + I): s += xw_i ; t += (e_ii?3:1)*xw2_i ;
//   rs = rowsum+1 ; sumsq = rowsum - e_ii + (e_ii+1)^2 ; denom = rs^2 - sumsq
//   norm = denom==0 ? 0 : 1/denom ; out = norm*(s^2 - t) + bias
//
// R8 analysis: dur_us includes harness reset (~565us fill+restore tax); our spmm
// ~220us vs ~100us HBM floor => latency-bound (2-3 waves/SIMD, shallow lookahead).
// v3: 8 waves x 16 rows (acc 32 VGPR, ~100 total), launch_bounds(512,4) => 4
// waves/SIMD, explicit next-step E prefetch, NT hint reverted.

#define NN 12288
#define IN_CH 64
#define OUT_CH 32
#define KC 8               // K chunks
#define KPC (NN / KC)      // 1536
#define NSTEP (KPC / 32)   // 48 K32-steps per chunk
#define MB 128             // rows per block (8 waves x 16 rows)
#define NMB (NN / MB)      // 96
#define NKSTEP (NN / 32)   // 384 total K32 steps

typedef __attribute__((ext_vector_type(8))) short short8;
typedef __attribute__((ext_vector_type(4))) float f32x4;

static __device__ __forceinline__ unsigned short f2bf_rn(float f) {
    unsigned int u = __float_as_uint(f);
    u += 0x7fffu + ((u >> 16) & 1u);   // round-to-nearest-even
    return (unsigned short)(u >> 16);
}

// ---------------- kernel 1: XW = x @ w (fp32, kept for epilogue) ----------------
__global__ __launch_bounds__(256) void build_xw(const float* __restrict__ x,
                                                const float* __restrict__ w,
                                                float* __restrict__ XW) {
    int t = blockIdx.x * blockDim.x + threadIdx.x;
    int i = t >> 5;
    int c = t & 31;
    if (i >= NN) return;
    float acc = 0.f;
#pragma unroll
    for (int k4 = 0; k4 < IN_CH / 4; ++k4) {
        f32x4 xv = *(const f32x4*)&x[(size_t)i * IN_CH + k4 * 4];
        acc = fmaf(xv.x, w[(k4 * 4 + 0) * OUT_CH + c], acc);
        acc = fmaf(xv.y, w[(k4 * 4 + 1) * OUT_CH + c], acc);
        acc = fmaf(xv.z, w[(k4 * 4 + 2) * OUT_CH + c], acc);
        acc = fmaf(xv.w, w[(k4 * 4 + 3) * OUT_CH + c], acc);
    }
    XW[(size_t)i * OUT_CH + c] = acc;
}

// ---------------- kernel 2: pack B into MFMA fragment order ----------------
// Bp[((s8*8 + t)*64 + lane)*4 + d] : u32 = bf16 pair for k = s8*32+(lane>>4)*8+2d (+1),
// col = t*16 + (lane&15). col<64 -> hi half, col>=64 -> lo half; (col&63)>=32 -> squared.
__global__ __launch_bounds__(256) void packb(const float* __restrict__ XW,
                                             unsigned int* __restrict__ Bp) {
    int idx = blockIdx.x * 256 + threadIdx.x;       // NKSTEP*512 threads
    int s = idx >> 9;
    int rem = idx & 511;
    int t = rem >> 6;
    int l = rem & 63;
    int kbase = s * 32 + ((l >> 4) * 8);
    int col = t * 16 + (l & 15);
    int cc = col & 31;
    bool sq = (col & 63) >= 32;
    bool lo = col >= 64;
    unsigned int out[4];
#pragma unroll
    for (int d = 0; d < 4; ++d) {
        unsigned short h[2];
#pragma unroll
        for (int j = 0; j < 2; ++j) {
            float v = XW[(size_t)(kbase + 2 * d + j) * OUT_CH + cc];
            if (sq) v *= v;
            unsigned short hb = f2bf_rn(v);
            if (lo) {
                float hf = __uint_as_float((unsigned int)hb << 16);
                hb = f2bf_rn(v - hf);
            }
            h[j] = hb;
        }
        out[d] = (unsigned int)h[0] | ((unsigned int)h[1] << 16);
    }
    *(uint4*)&Bp[(size_t)idx * 4] = *(uint4*)out;
}

// ---------------- kernel 3: streamed MFMA C = E @ B, slim waves ----------------
// grid = NMB*KC blocks of 512 (8 waves x 16-row strips). Explicit 1-step E prefetch.
// Ssl fragment index: (((kc*NMB+mb)*8 + w)*4 + t)*256 + lane*4 + r   (t = merged tile)
__global__ __launch_bounds__(512, 4) void spmm(const float* __restrict__ E,
                                               const unsigned int* __restrict__ Bp,
                                               float* __restrict__ Ssl,
                                               float* __restrict__ RSsl) {
    const int mb = blockIdx.x % NMB;
    const int kc = blockIdx.x / NMB;
    const int tid = threadIdx.x;
    const int w = tid >> 6;
    const int lane = tid & 63;
    const int r0 = mb * MB + w * 16;            // wave's 16-row strip
    const int row0 = r0 + (lane & 15);
    const int kq = (lane >> 4) * 8;             // k offset within the 32-step

    f32x4 acc[8] = {};
    float rs = 0.f;

    const float* ep = E + (size_t)row0 * NN + kc * KPC + kq;

    // prefetch step 0
    f32x4 a0n = *(const f32x4*)(ep);
    f32x4 a1n = *(const f32x4*)(ep + 4);

    for (int s = 0; s < NSTEP; ++s) {
        f32x4 a0 = a0n, a1 = a1n;
        if (s + 1 < NSTEP) {                    // issue next-step loads early
            a0n = *(const f32x4*)(ep + (s + 1) * 32);
            a1n = *(const f32x4*)(ep + (s + 1) * 32 + 4);
        }
        const unsigned int* bp = Bp + (size_t)(kc * NSTEP + s) * 2048 + lane * 4;
        uint4 b[8];
#pragma unroll
        for (int t = 0; t < 8; ++t)
            b[t] = *(const uint4*)(bp + t * 256);

        // pack E to bf16 (exact: values are 0.0/1.0, truncation lossless)
        union { unsigned int u[4]; short8 v; } pa;
        pa.u[0] = (__float_as_uint(a0.x) >> 16) | (__float_as_uint(a0.y) & 0xffff0000u);
        pa.u[1] = (__float_as_uint(a0.z) >> 16) | (__float_as_uint(a0.w) & 0xffff0000u);
        pa.u[2] = (__float_as_uint(a1.x) >> 16) | (__float_as_uint(a1.y) & 0xffff0000u);
        pa.u[3] = (__float_as_uint(a1.z) >> 16) | (__float_as_uint(a1.w) & 0xffff0000u);

        rs += ((a0.x + a0.y) + (a0.z + a0.w)) + ((a1.x + a1.y) + (a1.z + a1.w));

#pragma unroll
        for (int t = 0; t < 8; ++t) {
            union { uint4 q; short8 v; } bu;
            bu.q = b[t];
            acc[t] = __builtin_amdgcn_mfma_f32_16x16x32_bf16(pa.v, bu.v, acc[t], 0, 0, 0);
        }
    }

    // rowsum reduce: lanes {l, l+16, l+32, l+48} hold k-octet partials of one row
    rs += __shfl_xor(rs, 16, 64);
    rs += __shfl_xor(rs, 32, 64);
    if (lane < 16)
        RSsl[(size_t)kc * NN + r0 + lane] = rs;

    // store merged hi+lo fragments, fully coalesced (lane-major f32x4)
    const size_t base = (((size_t)kc * NMB + mb) * 8 + w) * 4;
#pragma unroll
    for (int t = 0; t < 4; ++t) {
        f32x4 v = acc[t] + acc[t + 4];
        *(f32x4*)&Ssl[(base + t) * 256 + lane * 4] = v;
    }
}

// ---------------- kernel 4: epilogue — slice reduce + norm + bias ----------------
__global__ __launch_bounds__(256) void epi(const float* __restrict__ E,
                                           const float* __restrict__ XW,
                                           const float* __restrict__ Ssl,
                                           const float* __restrict__ RSsl,
                                           const float* __restrict__ bias,
                                           float* __restrict__ out) {
    int tt0 = blockIdx.x * blockDim.x + threadIdx.x;  // NN*32 threads
    int i = tt0 >> 5;
    int c = tt0 & 31;
    if (i >= NN) return;
    // locate (i, ch) inside the spmm fragment layout
    const int mb = i >> 7;
    const int w = (i >> 4) & 7;
    const int rw = i & 15;
    const int lane_s = (rw >> 2) * 16 + (c & 15);
    const int r = rw & 3;
    const int ts = c >> 4;          // s-part tile; xw^2 part at ts+2
    float s = 0.f, tsum = 0.f, rse = 0.f;
#pragma unroll
    for (int kc = 0; kc < KC; ++kc) {
        const size_t base = (((size_t)kc * NMB + mb) * 8 + w) * 4;
        s    += Ssl[(base + ts) * 256 + lane_s * 4 + r];
        tsum += Ssl[(base + 2 + ts) * 256 + lane_s * 4 + r];
        rse  += RSsl[(size_t)kc * NN + i];
    }
    const float eii = E[(size_t)i * NN + i];            // 0 or 1
    const float xwc = XW[(size_t)i * OUT_CH + c];
    const float xw2c = xwc * xwc;
    s += xwc;
    tsum += (eii != 0.f ? 3.f : 1.f) * xw2c;
    const float rsa = rse + 1.f;
    const float d1 = eii + 1.f;
    const float sumsq = rse - eii + d1 * d1;
    const float denom = rsa * rsa - sumsq;
    const float nrm = (denom == 0.f) ? 0.f : 1.f / denom;
    out[(size_t)i * OUT_CH + c] = nrm * (s * s - tsum) + bias[c];
}

extern "C" void kernel_launch(void* const* d_in, const int* in_sizes, int n_in,
                              void* d_out, int out_size, void* d_ws, size_t ws_size,
                              hipStream_t stream) {
    const float* x    = (const float*)d_in[0];
    const float* E    = (const float*)d_in[1];
    const float* w    = (const float*)d_in[2];
    const float* bias = (const float*)d_in[3];
    float* out = (float*)d_out;

    // ws layout: XW [NN*32] f32 | Bp [NKSTEP*512*4] u32 | Ssl [KC*NMB*8*4*256] f32
    //            | RSsl [KC*NN] f32   (~30 MB total; everything written before read)
    float* XW = (float*)d_ws;
    unsigned int* Bp = (unsigned int*)(XW + (size_t)NN * OUT_CH);
    float* Ssl = (float*)(Bp + (size_t)NKSTEP * 512 * 4);
    float* RSsl = Ssl + (size_t)KC * NMB * 8 * 4 * 256;

    build_xw<<<NN * OUT_CH / 256, 256, 0, stream>>>(x, w, XW);
    packb<<<NKSTEP * 512 / 256, 256, 0, stream>>>(XW, Bp);
    spmm<<<NMB * KC, 512, 0, stream>>>(E, Bp, Ssl, RSsl);
    epi<<<NN * OUT_CH / 256, 256, 0, stream>>>(E, XW, Ssl, RSsl, bias, out);
}

// Round 10
// 821.122 us; speedup vs baseline: 1.0720x; 1.0720x over previous
//
#include <hip/hip_runtime.h>

// BGNN-A fused kernel for MI355X (gfx950) — R3 structure (best measured: 818us)
// + spmm register diet for 4 waves/SIMD + setprio around MFMA.
// Inputs (fp32): x[12288,64], edge_index[12288,12288] (binary 0/1), weight[64,32], bias[32]
// out (fp32): [12288, 32]
//
// Math (binary off-diagonal adjacency => E^2 == E off-diagonal):
//   xw = x @ w; B channels (128): [hi(xw)|hi(xw^2)|lo(xw)|lo(xw^2)] (bf16 hi/lo split)
//   C = E_bf16 @ B (MFMA fp32 accum); S[.,c] = C[.,c] + C[.,c+64]
//   rowsum_e[i] = sum_j E[i,j] (integer-exact VALU side-accumulate)
//   diag fixups (adj = E + I): s += xw_i ; t += (e_ii?3:1)*xw2_i ;
//   rs = rowsum+1 ; sumsq = rowsum - e_ii + (e_ii+1)^2 ; denom = rs^2 - sumsq
//   norm = denom==0 ? 0 : 1/denom ; out = norm*(s^2 - t) + bias
//
// Ledger: R3 (this structure, 3 waves/SIMD) = 818us. R8 slices = 836. R9 slim = 880.
// dur_us includes harness reset (~565-620us); controllable part ~200-250us vs ~140 floor.

#define NN 12288
#define IN_CH 64
#define OUT_CH 32
#define KC 8               // K chunks
#define KPC (NN / KC)      // 1536
#define NSTEP (KPC / 32)   // 48 K32-steps per chunk
#define MB 128             // rows per block (4 waves x 32 rows)
#define NMB (NN / MB)      // 96
#define NKSTEP (NN / 32)   // 384 total K32 steps

typedef __attribute__((ext_vector_type(8))) short short8;
typedef __attribute__((ext_vector_type(4))) float f32x4;

static __device__ __forceinline__ unsigned short f2bf_rn(float f) {
    unsigned int u = __float_as_uint(f);
    u += 0x7fffu + ((u >> 16) & 1u);   // round-to-nearest-even
    return (unsigned short)(u >> 16);
}

// ---------------- kernel 1: XW = x @ w (fp32, kept for epilogue) ----------------
__global__ __launch_bounds__(256) void build_xw(const float* __restrict__ x,
                                                const float* __restrict__ w,
                                                float* __restrict__ XW) {
    int t = blockIdx.x * blockDim.x + threadIdx.x;
    int i = t >> 5;
    int c = t & 31;
    if (i >= NN) return;
    float acc = 0.f;
#pragma unroll
    for (int k4 = 0; k4 < IN_CH / 4; ++k4) {
        f32x4 xv = *(const f32x4*)&x[(size_t)i * IN_CH + k4 * 4];
        acc = fmaf(xv.x, w[(k4 * 4 + 0) * OUT_CH + c], acc);
        acc = fmaf(xv.y, w[(k4 * 4 + 1) * OUT_CH + c], acc);
        acc = fmaf(xv.z, w[(k4 * 4 + 2) * OUT_CH + c], acc);
        acc = fmaf(xv.w, w[(k4 * 4 + 3) * OUT_CH + c], acc);
    }
    XW[(size_t)i * OUT_CH + c] = acc;
}

// ---------------- kernel 2: pack B into MFMA fragment order ----------------
// Bp[((s*8 + t)*64 + lane)*4 + d] : u32 = bf16 pair for k = s*32+(lane>>4)*8+2d (+1),
// col = t*16 + (lane&15). col<64 -> hi half, col>=64 -> lo half; (col&63)>=32 -> squared.
__global__ __launch_bounds__(256) void packb(const float* __restrict__ XW,
                                             unsigned int* __restrict__ Bp) {
    int idx = blockIdx.x * 256 + threadIdx.x;       // NKSTEP*512 threads
    int s = idx >> 9;
    int rem = idx & 511;
    int t = rem >> 6;
    int l = rem & 63;
    int kbase = s * 32 + ((l >> 4) * 8);
    int col = t * 16 + (l & 15);
    int cc = col & 31;
    bool sq = (col & 63) >= 32;
    bool lo = col >= 64;
    unsigned int out[4];
#pragma unroll
    for (int d = 0; d < 4; ++d) {
        unsigned short h[2];
#pragma unroll
        for (int j = 0; j < 2; ++j) {
            float v = XW[(size_t)(kbase + 2 * d + j) * OUT_CH + cc];
            if (sq) v *= v;
            unsigned short hb = f2bf_rn(v);
            if (lo) {
                float hf = __uint_as_float((unsigned int)hb << 16);
                hb = f2bf_rn(v - hf);
            }
            h[j] = hb;
        }
        out[d] = (unsigned int)h[0] | ((unsigned int)h[1] << 16);
    }
    *(uint4*)&Bp[(size_t)idx * 4] = *(uint4*)out;
}

// ---------------- kernel 3: streamed MFMA C = E @ B, atomic fixup ----------------
// grid = NMB*KC blocks of 256 (4 waves x 32-row strips). Register diet: B loaded in
// two 4-fragment batches around the MFMA clusters -> ~115-125 VGPR, 4 waves/SIMD.
__global__ __launch_bounds__(256, 4) void spmm(const float* __restrict__ E,
                                               const unsigned int* __restrict__ Bp,
                                               float* __restrict__ S,
                                               float* __restrict__ RS) {
    const int mb = blockIdx.x % NMB;
    const int kc = blockIdx.x / NMB;
    const int tid = threadIdx.x;
    const int wid = tid >> 6;
    const int lane = tid & 63;
    const int r0 = mb * MB + wid * 32;          // wave's 32-row strip
    const int row0 = r0 + (lane & 15);          // mtile 0 row for this lane
    const int kq = (lane >> 4) * 8;             // k offset within the 32-step

    f32x4 acc[2][8] = {};
    float rs[2] = {0.f, 0.f};

    const float* e0p = E + (size_t)row0 * NN + kc * KPC + kq;
    const float* e1p = e0p + (size_t)16 * NN;

    for (int s = 0; s < NSTEP; ++s) {
        const int koff = s * 32;
        f32x4 a0 = *(const f32x4*)(e0p + koff);
        f32x4 a1 = *(const f32x4*)(e0p + koff + 4);
        f32x4 c0 = *(const f32x4*)(e1p + koff);
        f32x4 c1 = *(const f32x4*)(e1p + koff + 4);

        const unsigned int* bp = Bp + (size_t)(kc * NSTEP + s) * 2048 + lane * 4;

        // batch 0 of B fragments
        uint4 b0[4];
#pragma unroll
        for (int t = 0; t < 4; ++t)
            b0[t] = *(const uint4*)(bp + t * 256);

        // pack E to bf16 (exact: values are 0.0/1.0, truncation lossless)
        union { unsigned int u[4]; short8 v; } pa, pb;
        pa.u[0] = (__float_as_uint(a0.x) >> 16) | (__float_as_uint(a0.y) & 0xffff0000u);
        pa.u[1] = (__float_as_uint(a0.z) >> 16) | (__float_as_uint(a0.w) & 0xffff0000u);
        pa.u[2] = (__float_as_uint(a1.x) >> 16) | (__float_as_uint(a1.y) & 0xffff0000u);
        pa.u[3] = (__float_as_uint(a1.z) >> 16) | (__float_as_uint(a1.w) & 0xffff0000u);
        pb.u[0] = (__float_as_uint(c0.x) >> 16) | (__float_as_uint(c0.y) & 0xffff0000u);
        pb.u[1] = (__float_as_uint(c0.z) >> 16) | (__float_as_uint(c0.w) & 0xffff0000u);
        pb.u[2] = (__float_as_uint(c1.x) >> 16) | (__float_as_uint(c1.y) & 0xffff0000u);
        pb.u[3] = (__float_as_uint(c1.z) >> 16) | (__float_as_uint(c1.w) & 0xffff0000u);

        rs[0] += ((a0.x + a0.y) + (a0.z + a0.w)) + ((a1.x + a1.y) + (a1.z + a1.w));
        rs[1] += ((c0.x + c0.y) + (c0.z + c0.w)) + ((c1.x + c1.y) + (c1.z + c1.w));

        __builtin_amdgcn_s_setprio(1);
#pragma unroll
        for (int t = 0; t < 4; ++t) {
            union { uint4 q; short8 v; } bu;
            bu.q = b0[t];
            acc[0][t] = __builtin_amdgcn_mfma_f32_16x16x32_bf16(pa.v, bu.v, acc[0][t], 0, 0, 0);
            acc[1][t] = __builtin_amdgcn_mfma_f32_16x16x32_bf16(pb.v, bu.v, acc[1][t], 0, 0, 0);
        }
        __builtin_amdgcn_s_setprio(0);

        // batch 1 of B fragments
        uint4 b1[4];
#pragma unroll
        for (int t = 0; t < 4; ++t)
            b1[t] = *(const uint4*)(bp + (4 + t) * 256);

        __builtin_amdgcn_s_setprio(1);
#pragma unroll
        for (int t = 0; t < 4; ++t) {
            union { uint4 q; short8 v; } bu;
            bu.q = b1[t];
            acc[0][4 + t] = __builtin_amdgcn_mfma_f32_16x16x32_bf16(pa.v, bu.v, acc[0][4 + t], 0, 0, 0);
            acc[1][4 + t] = __builtin_amdgcn_mfma_f32_16x16x32_bf16(pb.v, bu.v, acc[1][4 + t], 0, 0, 0);
        }
        __builtin_amdgcn_s_setprio(0);
    }

    // rowsum reduce: lanes {l, l+16, l+32, l+48} hold k-octet partials of one row
#pragma unroll
    for (int m = 0; m < 2; ++m) {
        float v = rs[m];
        v += __shfl_xor(v, 16, 64);
        v += __shfl_xor(v, 32, 64);
        if ((lane >> 4) == 0)
            atomicAdd(&RS[r0 + m * 16 + (lane & 15)], v);
    }

    // C/D layout (m89-verified): col = lane&15, row = (lane>>4)*4 + reg
    // merge hi (tile t) + lo (tile t+4) channel halves before the atomic
#pragma unroll
    for (int m = 0; m < 2; ++m) {
        const int rowb = r0 + m * 16 + (lane >> 4) * 4;
#pragma unroll
        for (int t = 0; t < 4; ++t) {
#pragma unroll
            for (int r = 0; r < 4; ++r) {
                float v = acc[m][t][r] + acc[m][t + 4][r];
                atomicAdd(&S[(size_t)(rowb + r) * 64 + t * 16 + (lane & 15)], v);
            }
        }
    }
}

// ---------------- kernel 4: epilogue ----------------
__global__ __launch_bounds__(256) void epi(const float* __restrict__ E,
                                           const float* __restrict__ XW,
                                           const float* __restrict__ S,
                                           const float* __restrict__ RS,
                                           const float* __restrict__ bias,
                                           float* __restrict__ out) {
    int t = blockIdx.x * blockDim.x + threadIdx.x;  // NN*32 threads
    int i = t >> 5;
    int c = t & 31;
    if (i >= NN) return;
    const float eii = E[(size_t)i * NN + i];            // 0 or 1
    const float xwc = XW[(size_t)i * OUT_CH + c];
    const float xw2c = xwc * xwc;
    const float s = S[(size_t)i * 64 + c] + xwc;
    const float tt = S[(size_t)i * 64 + 32 + c] + (eii != 0.f ? 3.f : 1.f) * xw2c;
    const float rse = RS[i];
    const float rsa = rse + 1.f;
    const float d1 = eii + 1.f;
    const float sumsq = rse - eii + d1 * d1;
    const float denom = rsa * rsa - sumsq;
    const float nrm = (denom == 0.f) ? 0.f : 1.f / denom;
    out[(size_t)i * OUT_CH + c] = nrm * (s * s - tt) + bias[c];
}

extern "C" void kernel_launch(void* const* d_in, const int* in_sizes, int n_in,
                              void* d_out, int out_size, void* d_ws, size_t ws_size,
                              hipStream_t stream) {
    const float* x    = (const float*)d_in[0];
    const float* E    = (const float*)d_in[1];
    const float* w    = (const float*)d_in[2];
    const float* bias = (const float*)d_in[3];
    float* out = (float*)d_out;

    // ws layout: XW [NN*32] f32 | Bp [NKSTEP*512*4] u32 | S [NN*64] f32 | RS [NN] f32 (~8 MB)
    float* XW = (float*)d_ws;
    unsigned int* Bp = (unsigned int*)(XW + (size_t)NN * OUT_CH);
    float* S = (float*)(Bp + (size_t)NKSTEP * 512 * 4);
    float* RS = S + (size_t)NN * 64;

    // zero accumulators (ws is re-poisoned 0xAA before every timed launch)
    hipMemsetAsync(S, 0, ((size_t)NN * 64 + NN) * sizeof(float), stream);

    build_xw<<<NN * OUT_CH / 256, 256, 0, stream>>>(x, w, XW);
    packb<<<NKSTEP * 512 / 256, 256, 0, stream>>>(XW, Bp);
    spmm<<<NMB * KC, 256, 0, stream>>>(E, Bp, S, RS);
    epi<<<NN * OUT_CH / 256, 256, 0, stream>>>(E, XW, S, RS, bias, out);
}